// Round 2
// baseline (748.276 us; speedup 1.0000x reference)
//
#include <hip/hip_runtime.h>
#include <cstdint>

#define HIDDEN 128
#define MTOT 16

// ---------------------------------------------------------------------------
// Zero-fill d_out (replaces pathologically slow graph-captured hipMemsetAsync:
// measured 488us for 3.2MB in R0's profile).
// ---------------------------------------------------------------------------
__global__ __launch_bounds__(256) void zero_kernel(float4* __restrict__ out,
                                                   int n4) {
  int i = blockIdx.x * 256 + threadIdx.x;
  int stride = gridDim.x * 256;
  float4 z = {0.f, 0.f, 0.f, 0.f};
  for (; i < n4; i += stride) out[i] = z;
}

// ---------------------------------------------------------------------------
// q/k projection: out[r][j] = scale * sum_d x[r][d] * W[j][d]
// W staged in LDS (64KB) with XOR swizzle for conflict-free column reads.
// Each thread owns one output column; x row values broadcast via float4 loads.
// ---------------------------------------------------------------------------
__global__ __launch_bounds__(256) void proj_kernel(
    const float* __restrict__ x, const float* __restrict__ W,
    float* __restrict__ out, int n_rows, float scale) {
  __shared__ float sW[128 * 128];  // 64 KB, XOR-swizzled layout
  for (int i = threadIdx.x; i < 128 * 128; i += 256) {
    int j = i >> 7, d = i & 127;
    sW[j * 128 + (d ^ (j & 31))] = W[i] * scale;
  }
  __syncthreads();

  const int col  = threadIdx.x & 127;
  const int rpar = threadIdx.x >> 7;  // 0 or 1: even/odd rows
  const int cx   = col & 31;
  const float* sWc = sW + col * 128;

  int row0 = blockIdx.x * 64;
  int rend = min(row0 + 64, n_rows);
  for (int r = row0 + rpar; r < rend; r += 2) {
    const float4* xr = (const float4*)(x + (size_t)r * HIDDEN);
    float a0 = 0.f, a1 = 0.f, a2 = 0.f, a3 = 0.f;
#pragma unroll
    for (int d4 = 0; d4 < 32; ++d4) {
      float4 xv = xr[d4];  // broadcast across wave (all lanes same row)
      int d = d4 * 4;
      a0 += xv.x * sWc[(d + 0) ^ cx];
      a1 += xv.y * sWc[(d + 1) ^ cx];
      a2 += xv.z * sWc[(d + 2) ^ cx];
      a3 += xv.w * sWc[(d + 3) ^ cx];
    }
    out[(size_t)r * HIDDEN + col] = (a0 + a1) + (a2 + a3);
  }
}

// ---------------------------------------------------------------------------
// Edge kernel: 32 lanes per edge. Lane i covers dims 4i..4i+3.
// Head h = lane/8 (8 lanes * 4 dims = 32 dims per head).
// shfl_xor(1,2,4) reduces within each 8-lane head group.
// Lanes 0..15 scatter the 16 spherical components (head-of-m via compares).
// ---------------------------------------------------------------------------
__global__ __launch_bounds__(256) void edge_kernel(
    const float* __restrict__ q, const float* __restrict__ k,
    const float* __restrict__ w_ij, const float* __restrict__ sph,
    const int* __restrict__ ei, const float* __restrict__ cutoff,
    float* __restrict__ out, int E, int ngroups) {
  const int g0       = blockIdx.x * 8 + (threadIdx.x >> 5);
  const int lane     = threadIdx.x & 31;
  const int halfbase = threadIdx.x & 32;  // which 32-lane group of the wave
  // m -> head: m0->h0, m1..3->h1, m4..8->h2, m9..15->h3
  const int h_for_m  = (lane >= 1) + (lane >= 4) + (lane >= 9);
  const int srcLane  = halfbase + (h_for_m << 3);

  for (int e = g0; e < E; e += ngroups) {
    int src = ei[e];
    int dst = ei[E + e];
    float4 w4 = ((const float4*)(w_ij + (size_t)e * HIDDEN))[lane];
    float4 q4 = ((const float4*)(q + (size_t)dst * HIDDEN))[lane];
    float4 k4 = ((const float4*)(k + (size_t)src * HIDDEN))[lane];
    float p = q4.x * w4.x * k4.x + q4.y * w4.y * k4.y +
              q4.z * w4.z * k4.z + q4.w * w4.w * k4.w;
    p += __shfl_xor(p, 1);
    p += __shfl_xor(p, 2);
    p += __shfl_xor(p, 4);
    // all 8 lanes of head group h now hold alpha_raw[h] (scale folded into q)
    float alpha = p * cutoff[e];
    float am = __shfl(alpha, srcLane);  // fetch the head this m needs
    if (lane < 16) {
      atomicAdd(out + (size_t)dst * MTOT + lane,
                am * sph[(size_t)e * MTOT + lane]);
    }
  }
}

extern "C" void kernel_launch(void* const* d_in, const int* in_sizes, int n_in,
                              void* d_out, int out_size, void* d_ws, size_t ws_size,
                              hipStream_t stream) {
  // inputs: chi, sph_ij, x, w_ij, edge_index, cutoff, Wq, Wk
  const float* sph    = (const float*)d_in[1];
  const float* x      = (const float*)d_in[2];
  const float* w_ij   = (const float*)d_in[3];
  const int*   ei     = (const int*)d_in[4];
  const float* cutoff = (const float*)d_in[5];
  const float* Wq     = (const float*)d_in[6];
  const float* Wk     = (const float*)d_in[7];
  float* out = (float*)d_out;

  const int n_nodes = in_sizes[0] / MTOT;  // chi is [N, 16]
  const int E       = in_sizes[5];         // cutoff is [E, 1]

  float* q = (float*)d_ws;
  float* k = q + (size_t)n_nodes * HIDDEN;

  // zero d_out with our own kernel (graph-captured hipMemsetAsync measured
  // 488us for 3.2MB in R0 rocprof -- rocclr fill path is broken here)
  const int n4 = out_size / 4;  // out_size = 800000, divisible by 4
  zero_kernel<<<256, 256, 0, stream>>>((float4*)out, n4);

  const int pgrid = (n_nodes + 63) / 64;
  const float inv_sqrt_hd = 0.17677669529663687f;  // 1/sqrt(32)
  proj_kernel<<<pgrid, 256, 0, stream>>>(x, Wq, q, n_nodes, inv_sqrt_hd);
  proj_kernel<<<pgrid, 256, 0, stream>>>(x, Wk, k, n_nodes, 1.0f);

  const int NB = 20000;                  // 160000 groups -> exactly 10 edges each
  const int ngroups = NB * 8;
  edge_kernel<<<NB, 256, 0, stream>>>(q, k, w_ij, sph, ei, cutoff, out, E, ngroups);
}

// Round 4
// 506.586 us; speedup vs baseline: 1.4771x; 1.4771x over previous
//
#include <hip/hip_runtime.h>
#include <hip/hip_fp16.h>
#include <cstdint>

#define HIDDEN 128
#define MTOT 16

typedef float vfloat4 __attribute__((ext_vector_type(4)));  // native vec for nontemporal builtins

// ---------------------------------------------------------------------------
// Zero-fill d_out (harness poisons d_out with 0xAA; graph must re-zero).
// ---------------------------------------------------------------------------
__global__ __launch_bounds__(256) void zero_kernel(float4* __restrict__ out,
                                                   int n4) {
  int i = blockIdx.x * 256 + threadIdx.x;
  int stride = gridDim.x * 256;
  float4 z = {0.f, 0.f, 0.f, 0.f};
  for (; i < n4; i += stride) out[i] = z;
}

// ---------------------------------------------------------------------------
// q/k projection, fp16 output: out[r][j] = (half) scale * sum_d x[r][d]*W[j][d]
// W staged in LDS with float4-preserving XOR swizzle ((d&~3) ^ ((j&7)<<2)):
// ds_read_b128 per 4 dims, banks spread across 8 groups -> conflict-free.
// 4-row unroll: one ds_read_b128 feeds 16 FMAs (LDS traffic /4 vs 1-row).
// ---------------------------------------------------------------------------
__global__ __launch_bounds__(256) void proj_kernel(
    const float* __restrict__ x, const float* __restrict__ W,
    __half* __restrict__ out, int n_rows, float scale) {
  __shared__ float sW[128 * 128];  // 64 KB, swizzled
  for (int i = threadIdx.x; i < 128 * 128; i += 256) {
    int j = i >> 7, d = i & 127;
    sW[j * 128 + (d ^ ((j & 7) << 2))] = W[i] * scale;
  }
  __syncthreads();

  const int col = threadIdx.x & 127;
  const int g   = threadIdx.x >> 7;        // 0 or 1
  const int sx  = (col & 7) << 2;          // swizzle term (dword units)
  const float* sWc = sW + col * 128;

  const int row0 = blockIdx.x * 64;
#pragma unroll 1
  for (int m = 0; m < 8; ++m) {
    int r0 = row0 + g * 4 + m * 8;
    if (r0 >= n_rows) break;
    const float4* x4 = (const float4*)(x + (size_t)r0 * HIDDEN);
    float a0 = 0.f, a1 = 0.f, a2 = 0.f, a3 = 0.f;
    if (r0 + 3 < n_rows) {
#pragma unroll
      for (int d4 = 0; d4 < 32; ++d4) {
        float4 w4 = *(const float4*)(sWc + ((d4 << 2) ^ sx));
        float4 xv0 = x4[d4];
        float4 xv1 = x4[32 + d4];
        float4 xv2 = x4[64 + d4];
        float4 xv3 = x4[96 + d4];
        a0 += xv0.x * w4.x + xv0.y * w4.y + xv0.z * w4.z + xv0.w * w4.w;
        a1 += xv1.x * w4.x + xv1.y * w4.y + xv1.z * w4.z + xv1.w * w4.w;
        a2 += xv2.x * w4.x + xv2.y * w4.y + xv2.z * w4.z + xv2.w * w4.w;
        a3 += xv3.x * w4.x + xv3.y * w4.y + xv3.z * w4.z + xv3.w * w4.w;
      }
      out[(size_t)(r0 + 0) * HIDDEN + col] = __float2half(a0);
      out[(size_t)(r0 + 1) * HIDDEN + col] = __float2half(a1);
      out[(size_t)(r0 + 2) * HIDDEN + col] = __float2half(a2);
      out[(size_t)(r0 + 3) * HIDDEN + col] = __float2half(a3);
    } else {
      for (int r = r0; r < n_rows; ++r) {
        const float4* xr = (const float4*)(x + (size_t)r * HIDDEN);
        float a = 0.f;
        for (int d4 = 0; d4 < 32; ++d4) {
          float4 w4 = *(const float4*)(sWc + ((d4 << 2) ^ sx));
          float4 xv = xr[d4];
          a += xv.x * w4.x + xv.y * w4.y + xv.z * w4.z + xv.w * w4.w;
        }
        out[(size_t)r * HIDDEN + col] = __float2half(a);
      }
    }
  }
}

// ---------------------------------------------------------------------------
// Edge kernel: 32 lanes per edge, fp16 q/k (tables 25.6 MB -> L2-resident),
// nontemporal loads for the one-pass streams (w_ij, sph, ei, cutoff) so they
// don't evict q/k from L2.
// ---------------------------------------------------------------------------
__global__ __launch_bounds__(256) void edge_kernel(
    const __half* __restrict__ q, const __half* __restrict__ k,
    const float* __restrict__ w_ij, const float* __restrict__ sph,
    const int* __restrict__ ei, const float* __restrict__ cutoff,
    float* __restrict__ out, int E, int ngroups) {
  const int g0       = blockIdx.x * 8 + (threadIdx.x >> 5);
  const int lane     = threadIdx.x & 31;
  const int halfbase = threadIdx.x & 32;
  // m -> head: m0->h0, m1..3->h1, m4..8->h2, m9..15->h3
  const int h_for_m  = (lane >= 1) + (lane >= 4) + (lane >= 9);
  const int srcLane  = halfbase + (h_for_m << 3);

  for (int e = g0; e < E; e += ngroups) {
    int src = __builtin_nontemporal_load(ei + e);
    int dst = __builtin_nontemporal_load(ei + E + e);
    vfloat4 w4 = __builtin_nontemporal_load(
        (const vfloat4*)(w_ij + (size_t)e * HIDDEN) + lane);
    union { uint2 u; __half2 h2[2]; } qa, ka;
    qa.u = *((const uint2*)(q + (size_t)dst * HIDDEN) + lane);
    ka.u = *((const uint2*)(k + (size_t)src * HIDDEN) + lane);
    float2 q01 = __half22float2(qa.h2[0]);
    float2 q23 = __half22float2(qa.h2[1]);
    float2 k01 = __half22float2(ka.h2[0]);
    float2 k23 = __half22float2(ka.h2[1]);
    float p = q01.x * w4.x * k01.x + q01.y * w4.y * k01.y +
              q23.x * w4.z * k23.x + q23.y * w4.w * k23.y;
    p += __shfl_xor(p, 1);
    p += __shfl_xor(p, 2);
    p += __shfl_xor(p, 4);
    float alpha = p * __builtin_nontemporal_load(cutoff + e);
    float am = __shfl(alpha, srcLane);
    if (lane < 16) {
      float s = __builtin_nontemporal_load(sph + (size_t)e * MTOT + lane);
      atomicAdd(out + (size_t)dst * MTOT + lane, am * s);
    }
  }
}

extern "C" void kernel_launch(void* const* d_in, const int* in_sizes, int n_in,
                              void* d_out, int out_size, void* d_ws, size_t ws_size,
                              hipStream_t stream) {
  // inputs: chi, sph_ij, x, w_ij, edge_index, cutoff, Wq, Wk
  const float* sph    = (const float*)d_in[1];
  const float* x      = (const float*)d_in[2];
  const float* w_ij   = (const float*)d_in[3];
  const int*   ei     = (const int*)d_in[4];
  const float* cutoff = (const float*)d_in[5];
  const float* Wq     = (const float*)d_in[6];
  const float* Wk     = (const float*)d_in[7];
  float* out = (float*)d_out;

  const int n_nodes = in_sizes[0] / MTOT;  // chi is [N, 16]
  const int E       = in_sizes[5];         // cutoff is [E, 1]

  __half* q = (__half*)d_ws;
  __half* k = q + (size_t)n_nodes * HIDDEN;

  const int n4 = out_size / 4;
  zero_kernel<<<256, 256, 0, stream>>>((float4*)out, n4);

  const int pgrid = (n_nodes + 63) / 64;
  const float inv_sqrt_hd = 0.17677669529663687f;  // 1/sqrt(32)
  proj_kernel<<<pgrid, 256, 0, stream>>>(x, Wq, q, n_nodes, inv_sqrt_hd);
  proj_kernel<<<pgrid, 256, 0, stream>>>(x, Wk, k, n_nodes, 1.0f);

  const int NB = 20000;  // 160000 groups -> exactly 10 edges each
  const int ngroups = NB * 8;
  edge_kernel<<<NB, 256, 0, stream>>>(q, k, w_ij, sph, ei, cutoff, out, E, ngroups);
}